// Round 1
// 495.902 us; speedup vs baseline: 1.0076x; 1.0076x over previous
//
#include <hip/hip_runtime.h>

#define NV 400000
#define KOFF 27
#define CD 64
#define DD 128
#define HH 128
#define WW 128
#define TABN (2*DD*HH*WW)
#define EPSV 1e-5f

typedef _Float16 f16;
typedef _Float16 f16x8 __attribute__((ext_vector_type(8)));
typedef float f32x16 __attribute__((ext_vector_type(16)));

// ---- workspace layout (bytes) ----
#define OFF_NBR   0ull
#define OFF_X1    43200000ull
#define OFF_X2    94400000ull
#define OFF_TAB   94400000ull     // table dead before x2 written
#define OFF_W2T   145600000ull
#define OFF_W3T   145821184ull
#define OFF_ZERO  146042368ull

#define GLDS16(gp, lp) __builtin_amdgcn_global_load_lds( \
    (__attribute__((address_space(1))) void*)(gp), \
    (__attribute__((address_space(3))) void*)(lp), 16, 0, 0)

// ---- init: table=-1; weights -> f16 chunk-major wTg[k][cin/8][cout][cin&7] ----
__global__ void k_init(const float* __restrict__ w2, const float* __restrict__ w3,
                       int* __restrict__ tab, f16* __restrict__ w2t,
                       f16* __restrict__ w3t, f16* __restrict__ zrow) {
    int t = blockIdx.x * 256 + threadIdx.x;           // grid: 4096*256
    int4* tv = (int4*)tab;
    if (t < TABN / 4) tv[t] = make_int4(-1, -1, -1, -1);
    if (t < KOFF * CD * CD) {
        int k = t >> 12, r = t & 4095, c = r >> 6, ci = r & 63;
        int d = (k << 12) + ((ci >> 3) << 9) + (c << 3) + (ci & 7);
        w2t[d] = (f16)w2[(k << 12) + (ci << 6) + c];
        w3t[d] = (f16)w3[(k << 12) + (ci << 6) + c];
    }
    if (t < CD) zrow[t] = (f16)0.f;
}

__global__ void k_scatter(const int4* __restrict__ coords, int* __restrict__ tab) {
    int i = blockIdx.x * 256 + threadIdx.x;
    if (i >= NV) return;
    int4 c = coords[i];  // (b,z,y,x)
    int flat = ((c.x * DD + c.y) * HH + c.z) * WW + c.w;
    tab[flat] = i;
}

__global__ void k_nbr(const int4* __restrict__ coords, const int* __restrict__ tab,
                      int* __restrict__ nbr) {
    int i = blockIdx.x * 256 + threadIdx.x;
    if (i >= NV) return;
    int4 c = coords[i];
    int k = 0;
    #pragma unroll
    for (int dz = -1; dz <= 1; dz++)
    #pragma unroll
    for (int dy = -1; dy <= 1; dy++)
    #pragma unroll
    for (int dx = -1; dx <= 1; dx++) {
        int z = c.y + dz, y = c.z + dy, x = c.w + dx;
        int idx = -1;
        if (z >= 0 && z < DD && y >= 0 && y < HH && x >= 0 && x < WW)
            idx = tab[((c.x * DD + z) * HH + y) * WW + x];
        nbr[k * NV + i] = idx;
        k++;
    }
}

// ---- layer 1: one thread per voxel, acc[64] in VGPRs, scalar weights ----
__global__ __launch_bounds__(256) void k_layer1(
        const float* __restrict__ feats, const int* __restrict__ nbr,
        const float* __restrict__ w1, const float* __restrict__ b1,
        const float* __restrict__ g1, const float* __restrict__ be1,
        const float* __restrict__ m1, const float* __restrict__ v1,
        f16* __restrict__ x1) {
    int i = blockIdx.x * 256 + threadIdx.x;
    bool act = (i < NV);
    int ii = act ? i : 0;

    float acc[CD];
    #pragma unroll
    for (int c = 0; c < CD; c++) acc[c] = 0.f;

    #pragma unroll
    for (int k = 0; k < KOFF; k++) {
        int idx = act ? nbr[k * NV + ii] : -1;
        float fk = (idx >= 0) ? feats[idx] : 0.f;
        #pragma unroll
        for (int c = 0; c < CD; c++)
            acc[c] = fmaf(fk, w1[k * CD + c], acc[c]);
    }
    if (!act) return;

    #pragma unroll
    for (int c0 = 0; c0 < CD; c0 += 8) {
        f16x8 o;
        #pragma unroll
        for (int j = 0; j < 8; j++) {
            int c = c0 + j;
            float sc = g1[c] * rsqrtf(v1[c] + EPSV);
            float y = (acc[c] - m1[c] + b1[c]) * sc + be1[c];
            o[j] = (f16)fmaxf(y, 0.f);
        }
        *(f16x8*)(x1 + (size_t)i * CD + c0) = o;
    }
}

// ---- conv v7: occupancy-first restructure.
// Block 256 thr / 4 waves / 128 voxels (32 voxels per wave), grid 3125 (exact).
// vs v6 (64 vox/wave): acc 64->32 AGPR, aF 64->32 VGPR (~144 -> ~85 regs/wave),
// epilogue scratch UNIONED with B-dbuf (LDS 48KB -> 16KB). Both caps move from
// 3 blocks/CU to 5 blocks/CU (launch_bounds(256,5)): 12 -> 20 waves/CU to fill
// the per-k barrier/vmcnt-drain stall (MfmaUtil was 31% with nothing saturated).
// nbr distribution: lane directly loads nbr[k*NV + row] for its own A-row
// (row = lane&31; halves g=0/1 duplicate the same 128B line) -> no ds_bpermute.
// Per k:
//  - B(k): 8KB weight tile, GLDS-staged once per block into LDS dbuf.
//  - A(k): per-lane 4x16B loads straight to VGPRs, predicated on idx>=0,
//    double-buffered in regs, prefetched one k ahead; nbr prefetched two ahead.
#define MFMA3216(a, b, c) __builtin_amdgcn_mfma_f32_32x32x16_f16(a, b, c, 0, 0, 0)

#define CONV_BODY(K, CUR, NXT)                                                  \
  {                                                                             \
    __syncthreads();                                                            \
    __builtin_amdgcn_sched_barrier(0);                                          \
    if ((K) + 1 < KOFF) {                                                       \
      _Pragma("unroll")                                                         \
      for (int it = 0; it < 2; it++) {                                          \
        const char* gp = (const char*)wT + ((size_t)((K) + 1) * 8192            \
                          + it * 4096 + tid * 16);                              \
        char* lp = (char*)bbuf + (NXT) * 8192 + it * 4096 + wv * 1024;          \
        GLDS16(gp, lp);                                                         \
      }                                                                         \
      if (idxN >= 0) {                                                          \
        const char* ap = (const char*)xin + (size_t)idxN * 128 + g * 16;        \
        _Pragma("unroll")                                                       \
        for (int ks = 0; ks < 4; ks++)                                          \
          aF[NXT][ks] = *(const f16x8*)(ap + ks * 32);                          \
      } else {                                                                  \
        _Pragma("unroll")                                                       \
        for (int ks = 0; ks < 4; ks++)                                          \
          aF[NXT][ks] = (f16x8)(f16)0.f;                                        \
      }                                                                         \
    }                                                                           \
    int iwN = -1;                                                               \
    if ((K) + 2 < KOFF)                                                         \
      iwN = nbr[(size_t)((K) + 2) * NV + row];                                  \
    __builtin_amdgcn_sched_barrier(0);                                          \
    _Pragma("unroll")                                                           \
    for (int ks = 0; ks < 4; ks++) {                                            \
      const char* bp = (const char*)bbuf + (CUR) * 8192 + (2 * ks + g) * 1024;  \
      f16x8 b0 = *(const f16x8*)(bp + ml * 16);                                 \
      f16x8 b1 = *(const f16x8*)(bp + 512 + ml * 16);                           \
      acc[0] = MFMA3216(aF[CUR][ks], b0, acc[0]);                               \
      acc[1] = MFMA3216(aF[CUR][ks], b1, acc[1]);                               \
    }                                                                           \
    __builtin_amdgcn_sched_barrier(0);                                          \
    idxN = iwN;                                                                 \
  }

static_assert(NV % 128 == 0, "grid must tile exactly");

template <bool OUTF32>
__global__ __launch_bounds__(256, 5) void k_conv(
        const f16* __restrict__ xin, const f16* __restrict__ wT,
        const int* __restrict__ nbr,
        const float* __restrict__ bb, const float* __restrict__ gg,
        const float* __restrict__ bee, const float* __restrict__ mm,
        const float* __restrict__ vv, void* __restrict__ outp) {
    // 16 KB total: B double-buffer [2][8192] during the loop; the SAME bytes
    // are the epilogue transpose scratch after the last MFMA (bbuf dead then).
    __shared__ __align__(16) unsigned char smem[16384];
    unsigned char* bbuf = smem;
    unsigned char* sS = smem;

    const int tid = threadIdx.x;
    const int lane = tid & 63;
    const int wv = tid >> 6;
    const int g = lane >> 5;
    const int ml = lane & 31;
    const int vbase = blockIdx.x * 128;       // grid 3125, exact fit
    const int row = vbase + wv * 32 + ml;     // this lane's A-row voxel

    f32x16 acc[2];
    #pragma unroll
    for (int b = 0; b < 2; b++) acc[b] = (f32x16)(0.f);

    f16x8 aF[2][4];
    int idxN;

    // prologue: stage B(0); idx(0) -> load A(0) into aF[0]; idx(1) -> idxN
    #pragma unroll
    for (int it = 0; it < 2; it++) {
        const char* gp = (const char*)wT + ((size_t)it * 4096 + tid * 16);
        char* lp = (char*)bbuf + it * 4096 + wv * 1024;
        GLDS16(gp, lp);
    }
    {
        int iw0 = nbr[row];
        if (iw0 >= 0) {
            const char* ap = (const char*)xin + (size_t)iw0 * 128 + g * 16;
            #pragma unroll
            for (int ks = 0; ks < 4; ks++)
                aF[0][ks] = *(const f16x8*)(ap + ks * 32);
        } else {
            #pragma unroll
            for (int ks = 0; ks < 4; ks++)
                aF[0][ks] = (f16x8)(f16)0.f;
        }
        idxN = nbr[(size_t)NV + row];
    }

    // 27 bodies: 13 pairs + final
    #pragma unroll 1
    for (int m = 0; m < 13; m++) {
        CONV_BODY(2 * m, 0, 1);
        CONV_BODY(2 * m + 1, 1, 0);
    }
    CONV_BODY(26, 0, 1);

    // epilogue: BN+ReLU -> LDS transpose -> vectorized stores
    if (!OUTF32) {
        __syncthreads();
        #pragma unroll
        for (int nt = 0; nt < 2; nt++) {
            int cn = nt * 32 + ml;
            float sc = gg[cn] * rsqrtf(vv[cn] + EPSV);
            float sh = (bb[cn] - mm[cn]) * sc + bee[cn];
            #pragma unroll
            for (int r = 0; r < 16; r++) {
                int rowl = wv * 32 + (r & 3) + 8 * (r >> 2) + 4 * g;
                float y = fmaxf(acc[nt][r] * sc + sh, 0.f);
                *(f16*)(sS + rowl * 128 + cn * 2) = (f16)y;
            }
        }
        __syncthreads();
        char* gb = (char*)outp + (size_t)vbase * 128;
        #pragma unroll
        for (int it = 0; it < 4; it++) {
            int s = it * 256 + tid;
            *(float4*)(gb + s * 16) = *(const float4*)(sS + s * 16);
        }
    } else {
        #pragma unroll 1
        for (int p = 0; p < 2; p++) {
            __syncthreads();
            if ((wv >> 1) == p) {
                int lw = wv & 1;
                #pragma unroll
                for (int nt = 0; nt < 2; nt++) {
                    int cn = nt * 32 + ml;
                    float sc = gg[cn] * rsqrtf(vv[cn] + EPSV);
                    float sh = (bb[cn] - mm[cn]) * sc + bee[cn];
                    #pragma unroll
                    for (int r = 0; r < 16; r++) {
                        int rowl = lw * 32 + (r & 3) + 8 * (r >> 2) + 4 * g;
                        float y = fmaxf(acc[nt][r] * sc + sh, 0.f);
                        *(float*)(sS + rowl * 256 + cn * 4) = y;
                    }
                }
            }
            __syncthreads();
            char* gb = (char*)outp + ((size_t)vbase + p * 64) * 256;
            #pragma unroll
            for (int it = 0; it < 4; it++) {
                int s = it * 256 + tid;
                *(float4*)(gb + s * 16) = *(const float4*)(sS + s * 16);
            }
        }
    }
}

extern "C" void kernel_launch(void* const* d_in, const int* in_sizes, int n_in,
                              void* d_out, int out_size, void* d_ws, size_t ws_size,
                              hipStream_t stream) {
    (void)in_sizes; (void)n_in; (void)out_size; (void)ws_size;
    const float* feats = (const float*)d_in[0];
    const int4* coords = (const int4*)d_in[1];
    const float* w1 = (const float*)d_in[2];
    const float* b1 = (const float*)d_in[3];
    const float* g1 = (const float*)d_in[4];
    const float* be1 = (const float*)d_in[5];
    const float* m1 = (const float*)d_in[6];
    const float* v1 = (const float*)d_in[7];
    const float* w2 = (const float*)d_in[8];
    const float* b2 = (const float*)d_in[9];
    const float* g2 = (const float*)d_in[10];
    const float* be2 = (const float*)d_in[11];
    const float* m2 = (const float*)d_in[12];
    const float* v2 = (const float*)d_in[13];
    const float* w3 = (const float*)d_in[14];
    const float* b3 = (const float*)d_in[15];
    const float* g3 = (const float*)d_in[16];
    const float* be3 = (const float*)d_in[17];
    const float* m3 = (const float*)d_in[18];
    const float* v3 = (const float*)d_in[19];

    char* ws = (char*)d_ws;
    int* nbr  = (int*)(ws + OFF_NBR);
    f16* x1   = (f16*)(ws + OFF_X1);
    f16* x2   = (f16*)(ws + OFF_X2);
    int* tab  = (int*)(ws + OFF_TAB);
    f16* w2t  = (f16*)(ws + OFF_W2T);
    f16* w3t  = (f16*)(ws + OFF_W3T);
    f16* zrow = (f16*)(ws + OFF_ZERO);

    k_init<<<4096, 256, 0, stream>>>(w2, w3, tab, w2t, w3t, zrow);
    k_scatter<<<(NV + 255) / 256, 256, 0, stream>>>(coords, tab);
    k_nbr<<<(NV + 255) / 256, 256, 0, stream>>>(coords, tab, nbr);
    k_layer1<<<(NV + 255) / 256, 256, 0, stream>>>(feats, nbr, w1, b1, g1, be1, m1, v1, x1);
    const int convgrid = NV / 128;  // 3125, exact
    k_conv<false><<<convgrid, 256, 0, stream>>>(x1, w2t, nbr, b2, g2, be2, m2, v2, (void*)x2);
    k_conv<true><<<convgrid, 256, 0, stream>>>(x2, w3t, nbr, b3, g3, be3, m3, v3, d_out);
}